// Round 2
// baseline (877.657 us; speedup 1.0000x reference)
//
#include <hip/hip_runtime.h>

// Problem constants
constexpr int NB = 8;    // batch
constexpr int NC = 32;   // channels
constexpr int NV = 512;  // vertices
constexpr int NL = 256;  // features
constexpr float F_ALPHA = 0.05f;
constexpr float F_BETA  = 0.95f;

typedef __bf16 bf16x8 __attribute__((ext_vector_type(8)));
typedef __bf16 bf16x4 __attribute__((ext_vector_type(4)));
typedef float  f32x4  __attribute__((ext_vector_type(4)));

// async global->LDS, 16B per lane; LDS dest = wave-uniform base + lane*16
__device__ __forceinline__ void async_ld16(const void* g, void* l) {
  __builtin_amdgcn_global_load_lds(
      (const __attribute__((address_space(1))) void*)g,
      (__attribute__((address_space(3))) void*)l, 16, 0, 0);
}

// ---------------- prep kernels ----------------

__global__ void k_colsum_part(const float* __restrict__ adj, float* __restrict__ partial) {
  int idx = blockIdx.x * 256 + threadIdx.x;       // NB*8*NV = 32768
  int w = idx & 511;
  int chunk = (idx >> 9) & 7;
  int n = idx >> 12;
  const float* p = adj + n * (NV * NV) + chunk * 64 * NV + w;
  float s = 0.f;
#pragma unroll
  for (int v = 0; v < 64; ++v) s += p[v * NV];
  partial[idx] = s;
}

__global__ void k_dinv(const float* __restrict__ partial, float* __restrict__ dinv) {
  int idx = blockIdx.x * 256 + threadIdx.x;       // NB*NV = 4096
  int w = idx & 511;
  int n = idx >> 9;
  float s = 1.f;
#pragma unroll
  for (int j = 0; j < 8; ++j) s += partial[n * 4096 + j * 512 + w];
  dinv[idx] = 1.f / s;
}

__global__ void k_prep_a(const float* __restrict__ adj, const float* __restrict__ dinv,
                         __bf16* __restrict__ a) {
  int idx = blockIdx.x * 256 + threadIdx.x;       // NB*NV*NV
  int w = idx & 511;
  int v = (idx >> 9) & 511;
  int n = idx >> 18;
  float val = adj[idx] + (v == w ? 1.0f : 0.0f);
  a[idx] = (__bf16)(val * dinv[(n << 9) | w]);
}

__global__ void k_prep_wt(const float* __restrict__ W, __bf16* __restrict__ Wt) {
  int idx = blockIdx.x * 256 + threadIdx.x;       // 65536
  int l = idx >> 8, k = idx & 255;
  Wt[idx] = (__bf16)W[(k << 8) | l];
}

// ---------------- GEMM 1: hw^T = Wt @ h^T + b ----------------
template <bool BF32>
__global__ __launch_bounds__(256, 2)
void k_gemm_wt(const __bf16* __restrict__ Wt, const void* __restrict__ Bsrc,
               const float* __restrict__ bias, __bf16* __restrict__ hw) {
  __shared__ __align__(16) char lds[32768];
  char* ldsA = lds;
  char* ldsB = lds + 16384;

  const int tid = threadIdx.x;
  const int bid = blockIdx.x;
  const int p = bid >> 3;
  const int mtile = (bid >> 2) & 1;
  const int ntile = bid & 3;
  const int n = p >> 5, c = p & 31;

  int Bbase, Bstride;
  if (BF32) { Bbase = p * (NV * NL); Bstride = NL; }
  else      { Bbase = n * (NV * NC * NL) + c * NL; Bstride = NC * NL; }

  const int wave = tid >> 6, lane = tid & 63;
  const int quad = lane >> 4, l16 = lane & 15;
  const int wm = wave >> 1, wn = wave & 1;
  const int wbase = (tid & ~63) * 16;

  f32x4 acc[4][4];
#pragma unroll
  for (int i = 0; i < 4; ++i)
#pragma unroll
    for (int j = 0; j < 4; ++j) acc[i][j] = (f32x4){0.f, 0.f, 0.f, 0.f};

  for (int kt = 0; kt < 256 / 64; ++kt) {
    __syncthreads();
#pragma unroll
    for (int j = 0; j < 4; ++j) {
      int pos = j * 4096 + tid * 16;
      int row = pos >> 7;
      int kb = (pos & 127) ^ ((row & 7) * 16);
      const __bf16* g = Wt + (mtile * 128 + row) * 256 + kt * 64 + (kb >> 1);
      async_ld16(g, ldsA + j * 4096 + wbase);
    }
    if (BF32) {
      const float* Bf = (const float*)Bsrc;
#pragma unroll
      for (int j = 0; j < 4; ++j) {
        int pos = j * 4096 + tid * 16;
        int row = pos >> 7;
        int kb = (pos & 127) ^ ((row & 7) * 16);
        const float* g = Bf + Bbase + (ntile * 128 + row) * Bstride + kt * 64 + (kb >> 1);
        float4 f0 = *(const float4*)g;
        float4 f1 = *(const float4*)(g + 4);
        bf16x8 vv;
        vv[0] = (__bf16)f0.x; vv[1] = (__bf16)f0.y; vv[2] = (__bf16)f0.z; vv[3] = (__bf16)f0.w;
        vv[4] = (__bf16)f1.x; vv[5] = (__bf16)f1.y; vv[6] = (__bf16)f1.z; vv[7] = (__bf16)f1.w;
        *(bf16x8*)(ldsB + pos) = vv;
      }
    } else {
      const __bf16* Bf = (const __bf16*)Bsrc;
#pragma unroll
      for (int j = 0; j < 4; ++j) {
        int pos = j * 4096 + tid * 16;
        int row = pos >> 7;
        int kb = (pos & 127) ^ ((row & 7) * 16);
        const __bf16* g = Bf + Bbase + (ntile * 128 + row) * Bstride + kt * 64 + (kb >> 1);
        async_ld16(g, ldsB + j * 4096 + wbase);
      }
    }
    __syncthreads();
#pragma unroll
    for (int ks = 0; ks < 2; ++ks) {
      bf16x8 af[4], bfr[4];
#pragma unroll
      for (int mb = 0; mb < 4; ++mb) {
        int m = wm * 64 + mb * 16 + l16;
        int kb = (ks * 64 + quad * 16) ^ ((m & 7) * 16);
        af[mb] = *(const bf16x8*)(ldsA + m * 128 + kb);
      }
#pragma unroll
      for (int nb = 0; nb < 4; ++nb) {
        int nn = wn * 64 + nb * 16 + l16;
        int kb = (ks * 64 + quad * 16) ^ ((nn & 7) * 16);
        bfr[nb] = *(const bf16x8*)(ldsB + nn * 128 + kb);
      }
#pragma unroll
      for (int mb = 0; mb < 4; ++mb)
#pragma unroll
        for (int nb = 0; nb < 4; ++nb)
          acc[mb][nb] = __builtin_amdgcn_mfma_f32_16x16x32_bf16(af[mb], bfr[nb], acc[mb][nb], 0, 0, 0);
    }
  }
  __bf16* outp = hw + p * (NL * NV) + mtile * 128 * NV + ntile * 128;
#pragma unroll
  for (int mb = 0; mb < 4; ++mb) {
#pragma unroll
    for (int r = 0; r < 4; ++r) {
      int ml = wm * 64 + mb * 16 + quad * 4 + r;
      float bv = bias[mtile * 128 + ml];
#pragma unroll
      for (int nb = 0; nb < 4; ++nb) {
        int nl = wn * 64 + nb * 16 + l16;
        outp[ml * NV + nl] = (__bf16)(acc[mb][nb][r] + bv);
      }
    }
  }
}

// ---------------- GEMM 2: h' = alpha*x + beta*(a @ hw) ----------------
__global__ __launch_bounds__(256, 2)
void k_gemm_a(const __bf16* __restrict__ abuf, const __bf16* __restrict__ hw,
              const float* __restrict__ x, __bf16* __restrict__ hout) {
  __shared__ __align__(16) char lds[32768];
  char* ldsA = lds;
  char* ldsB = lds + 16384;

  const int tid = threadIdx.x;
  const int bid = blockIdx.x;
  const int n = bid >> 8;
  const int mtile = (bid >> 6) & 3;
  const int ntile = bid & 63;

  const __bf16* Ab = abuf + n * (NV * NV) + mtile * 128 * NV;
  const __bf16* Bb = hw + n * (NC * NL * NV) + ntile * 128 * NV;

  const int wave = tid >> 6, lane = tid & 63;
  const int quad = lane >> 4, l16 = lane & 15;
  const int wm = wave >> 1, wn = wave & 1;
  const int wbase = (tid & ~63) * 16;

  f32x4 acc[4][4];
#pragma unroll
  for (int i = 0; i < 4; ++i)
#pragma unroll
    for (int j = 0; j < 4; ++j) acc[i][j] = (f32x4){0.f, 0.f, 0.f, 0.f};

  for (int kt = 0; kt < 512 / 64; ++kt) {
    __syncthreads();
#pragma unroll
    for (int j = 0; j < 4; ++j) {
      int pos = j * 4096 + tid * 16;
      int row = pos >> 7;
      int kb = (pos & 127) ^ ((row & 7) * 16);
      async_ld16(Ab + row * NV + kt * 64 + (kb >> 1), ldsA + j * 4096 + wbase);
    }
#pragma unroll
    for (int j = 0; j < 4; ++j) {
      int pos = j * 4096 + tid * 16;
      int row = pos >> 7;
      int kb = (pos & 127) ^ ((row & 7) * 16);
      async_ld16(Bb + row * NV + kt * 64 + (kb >> 1), ldsB + j * 4096 + wbase);
    }
    __syncthreads();
#pragma unroll
    for (int ks = 0; ks < 2; ++ks) {
      bf16x8 af[4], bfr[4];
#pragma unroll
      for (int mb = 0; mb < 4; ++mb) {
        int m = wm * 64 + mb * 16 + l16;
        int kb = (ks * 64 + quad * 16) ^ ((m & 7) * 16);
        af[mb] = *(const bf16x8*)(ldsA + m * 128 + kb);
      }
#pragma unroll
      for (int nb = 0; nb < 4; ++nb) {
        int nn = wn * 64 + nb * 16 + l16;
        int kb = (ks * 64 + quad * 16) ^ ((nn & 7) * 16);
        bfr[nb] = *(const bf16x8*)(ldsB + nn * 128 + kb);
      }
#pragma unroll
      for (int mb = 0; mb < 4; ++mb)
#pragma unroll
        for (int nb = 0; nb < 4; ++nb)
          acc[mb][nb] = __builtin_amdgcn_mfma_f32_16x16x32_bf16(af[mb], bfr[nb], acc[mb][nb], 0, 0, 0);
    }
  }
#pragma unroll
  for (int mb = 0; mb < 4; ++mb) {
#pragma unroll
    for (int r = 0; r < 4; ++r) {
      int v = mtile * 128 + wm * 64 + mb * 16 + quad * 4 + r;
#pragma unroll
      for (int nb = 0; nb < 4; ++nb) {
        int col = ntile * 128 + wn * 64 + nb * 16 + l16;
        int c = col >> 8, l = col & 255;
        float xv = x[((n * NC + c) * NV + v) * NL + l];
        hout[n * (NV * NC * NL) + v * (NC * NL) + col] =
            (__bf16)(F_ALPHA * xv + F_BETA * acc[mb][nb][r]);
      }
    }
  }
}

// ---------------- conv (vector fp32, no transpose, no staging sync) ----------------
// out[n,o,v,l] = cb[o] + sum_{k<96} w2[o,k]*cat(x,h1,h2)[n,k,v,l]
// thread owns (n, v, 4 consecutive l); 64 lanes of a wave span 256 l of one v.
__global__ __launch_bounds__(256, 2)
void k_conv_vec(const float* __restrict__ x, const __bf16* __restrict__ h1,
                const __bf16* __restrict__ h2, const float* __restrict__ cw,
                const float* __restrict__ cb, float* __restrict__ out) {
  __shared__ float w2s[32 * 96];  // 12 KiB, broadcast reads only
  const int tid = threadIdx.x;
  for (int i = tid; i < 32 * 96; i += 256) w2s[i] = cw[i];
  __syncthreads();

  const int bid = blockIdx.x;           // 1024 blocks: n(8) x vgroup(128)
  const int n = bid >> 7;
  const int v = ((bid & 127) << 2) + (tid >> 6);
  const int l = (tid & 63) << 2;

  const float*  px = x  + (n * NC * NV + v) * NL + l;     // + c*(NV*NL)
  const __bf16* p1 = h1 + (n * NV + v) * (NC * NL) + l;   // + c*NL
  const __bf16* p2 = h2 + (n * NV + v) * (NC * NL) + l;

  f32x4 acc[32];
#pragma unroll
  for (int o = 0; o < 32; ++o) acc[o] = (f32x4){0.f, 0.f, 0.f, 0.f};

#pragma unroll
  for (int kb = 0; kb < 12; ++kb) {
    f32x4 val[8];
#pragma unroll
    for (int j = 0; j < 8; ++j) {
      int k = kb * 8 + j;
      if (k < 32) {
        float4 t = *(const float4*)(px + k * (NV * NL));
        val[j] = (f32x4){t.x, t.y, t.z, t.w};
      } else if (k < 64) {
        bf16x4 t = *(const bf16x4*)(p1 + (k - 32) * NL);
        val[j] = (f32x4){(float)t[0], (float)t[1], (float)t[2], (float)t[3]};
      } else {
        bf16x4 t = *(const bf16x4*)(p2 + (k - 64) * NL);
        val[j] = (f32x4){(float)t[0], (float)t[1], (float)t[2], (float)t[3]};
      }
    }
#pragma unroll
    for (int o = 0; o < 32; ++o) {
      const float* wr = &w2s[o * 96 + kb * 8];
      f32x4 wA = *(const f32x4*)wr;
      f32x4 wB = *(const f32x4*)(wr + 4);
      acc[o] += val[0] * wA[0];
      acc[o] += val[1] * wA[1];
      acc[o] += val[2] * wA[2];
      acc[o] += val[3] * wA[3];
      acc[o] += val[4] * wB[0];
      acc[o] += val[5] * wB[1];
      acc[o] += val[6] * wB[2];
      acc[o] += val[7] * wB[3];
    }
  }

  float* po = out + (n * NC * NV + v) * NL + l;            // + o*(NV*NL)
#pragma unroll
  for (int o = 0; o < 32; ++o) {
    float bo = cb[o];
    f32x4 r = acc[o];
    float4 s = {r[0] + bo, r[1] + bo, r[2] + bo, r[3] + bo};
    *(float4*)(po + o * (NV * NL)) = s;
  }
}

// ---------------- launch ----------------
extern "C" void kernel_launch(void* const* d_in, const int* in_sizes, int n_in,
                              void* d_out, int out_size, void* d_ws, size_t ws_size,
                              hipStream_t stream) {
  const float* x   = (const float*)d_in[0];
  const float* adj = (const float*)d_in[1];
  const float* W   = (const float*)d_in[2];
  const float* b   = (const float*)d_in[3];
  const float* cw  = (const float*)d_in[4];
  const float* cb  = (const float*)d_in[5];
  float* out = (float*)d_out;
  char* ws = (char*)d_ws;

  float*  dinv    = (float*)ws;
  float*  partial = (float*)(ws + 16384);
  __bf16* Wt      = (__bf16*)(ws + 147456);
  __bf16* abuf    = (__bf16*)(ws + 278528);
  __bf16* hwbuf   = (__bf16*)(ws + 4472832);
  __bf16* h1      = (__bf16*)(ws + 4472832 + 67108864);
  __bf16* h2      = (__bf16*)(ws + 4472832 + 2 * 67108864);

  k_colsum_part<<<128, 256, 0, stream>>>(adj, partial);
  k_dinv<<<16, 256, 0, stream>>>(partial, dinv);
  k_prep_a<<<8192, 256, 0, stream>>>(adj, dinv, abuf);
  k_prep_wt<<<256, 256, 0, stream>>>(W, Wt);

  k_gemm_wt<true><<<2048, 256, 0, stream>>>(Wt, (const void*)x, b, hwbuf);
  k_gemm_a<<<2048, 256, 0, stream>>>(abuf, hwbuf, x, h1);
  k_gemm_wt<false><<<2048, 256, 0, stream>>>(Wt, (const void*)h1, b, hwbuf);
  k_gemm_a<<<2048, 256, 0, stream>>>(abuf, hwbuf, x, h2);

  k_conv_vec<<<1024, 256, 0, stream>>>(x, h1, h2, cw, cb, out);
}

// Round 3
// 543.266 us; speedup vs baseline: 1.6155x; 1.6155x over previous
//
#include <hip/hip_runtime.h>

// Problem constants
constexpr int NB = 8;    // batch
constexpr int NC = 32;   // channels
constexpr int NV = 512;  // vertices
constexpr int NL = 256;  // features
constexpr float F_ALPHA = 0.05f;
constexpr float F_BETA  = 0.95f;

typedef __bf16 bf16x8 __attribute__((ext_vector_type(8)));
typedef __bf16 bf16x2 __attribute__((ext_vector_type(2)));
typedef float  f32x4  __attribute__((ext_vector_type(4)));
typedef float  f32x2  __attribute__((ext_vector_type(2)));

// async global->LDS, 16B per lane; LDS dest = wave-uniform base + lane*16
__device__ __forceinline__ void async_ld16(const void* g, void* l) {
  __builtin_amdgcn_global_load_lds(
      (const __attribute__((address_space(1))) void*)g,
      (__attribute__((address_space(3))) void*)l, 16, 0, 0);
}

// ---------------- prep kernels ----------------

__global__ void k_colsum_part(const float* __restrict__ adj, float* __restrict__ partial) {
  int idx = blockIdx.x * 256 + threadIdx.x;       // NB*8*NV = 32768
  int w = idx & 511;
  int chunk = (idx >> 9) & 7;
  int n = idx >> 12;
  const float* p = adj + n * (NV * NV) + chunk * 64 * NV + w;
  float s = 0.f;
#pragma unroll
  for (int v = 0; v < 64; ++v) s += p[v * NV];
  partial[idx] = s;
}

__global__ void k_dinv(const float* __restrict__ partial, float* __restrict__ dinv) {
  int idx = blockIdx.x * 256 + threadIdx.x;       // NB*NV = 4096
  int w = idx & 511;
  int n = idx >> 9;
  float s = 1.f;
#pragma unroll
  for (int j = 0; j < 8; ++j) s += partial[n * 4096 + j * 512 + w];
  dinv[idx] = 1.f / s;
}

__global__ void k_prep_a(const float* __restrict__ adj, const float* __restrict__ dinv,
                         __bf16* __restrict__ a) {
  int idx = blockIdx.x * 256 + threadIdx.x;       // NB*NV*NV
  int w = idx & 511;
  int v = (idx >> 9) & 511;
  int n = idx >> 18;
  float val = adj[idx] + (v == w ? 1.0f : 0.0f);
  a[idx] = (__bf16)(val * dinv[(n << 9) | w]);
}

__global__ void k_prep_wt(const float* __restrict__ W, __bf16* __restrict__ Wt) {
  int idx = blockIdx.x * 256 + threadIdx.x;       // 65536
  int l = idx >> 8, k = idx & 255;
  Wt[idx] = (__bf16)W[(k << 8) | l];
}

// ---------------- GEMM 1: hw^T = Wt @ h^T + b ----------------
template <bool BF32>
__global__ __launch_bounds__(256, 2)
void k_gemm_wt(const __bf16* __restrict__ Wt, const void* __restrict__ Bsrc,
               const float* __restrict__ bias, __bf16* __restrict__ hw) {
  __shared__ __align__(16) char lds[32768];
  char* ldsA = lds;
  char* ldsB = lds + 16384;

  const int tid = threadIdx.x;
  const int bid = blockIdx.x;
  const int p = bid >> 3;
  const int mtile = (bid >> 2) & 1;
  const int ntile = bid & 3;
  const int n = p >> 5, c = p & 31;

  int Bbase, Bstride;
  if (BF32) { Bbase = p * (NV * NL); Bstride = NL; }
  else      { Bbase = n * (NV * NC * NL) + c * NL; Bstride = NC * NL; }

  const int wave = tid >> 6, lane = tid & 63;
  const int quad = lane >> 4, l16 = lane & 15;
  const int wm = wave >> 1, wn = wave & 1;
  const int wbase = (tid & ~63) * 16;

  f32x4 acc[4][4];
#pragma unroll
  for (int i = 0; i < 4; ++i)
#pragma unroll
    for (int j = 0; j < 4; ++j) acc[i][j] = (f32x4){0.f, 0.f, 0.f, 0.f};

  for (int kt = 0; kt < 256 / 64; ++kt) {
    __syncthreads();
#pragma unroll
    for (int j = 0; j < 4; ++j) {
      int pos = j * 4096 + tid * 16;
      int row = pos >> 7;
      int kb = (pos & 127) ^ ((row & 7) * 16);
      const __bf16* g = Wt + (mtile * 128 + row) * 256 + kt * 64 + (kb >> 1);
      async_ld16(g, ldsA + j * 4096 + wbase);
    }
    if (BF32) {
      const float* Bf = (const float*)Bsrc;
#pragma unroll
      for (int j = 0; j < 4; ++j) {
        int pos = j * 4096 + tid * 16;
        int row = pos >> 7;
        int kb = (pos & 127) ^ ((row & 7) * 16);
        const float* g = Bf + Bbase + (ntile * 128 + row) * Bstride + kt * 64 + (kb >> 1);
        float4 f0 = *(const float4*)g;
        float4 f1 = *(const float4*)(g + 4);
        bf16x8 vv;
        vv[0] = (__bf16)f0.x; vv[1] = (__bf16)f0.y; vv[2] = (__bf16)f0.z; vv[3] = (__bf16)f0.w;
        vv[4] = (__bf16)f1.x; vv[5] = (__bf16)f1.y; vv[6] = (__bf16)f1.z; vv[7] = (__bf16)f1.w;
        *(bf16x8*)(ldsB + pos) = vv;
      }
    } else {
      const __bf16* Bf = (const __bf16*)Bsrc;
#pragma unroll
      for (int j = 0; j < 4; ++j) {
        int pos = j * 4096 + tid * 16;
        int row = pos >> 7;
        int kb = (pos & 127) ^ ((row & 7) * 16);
        const __bf16* g = Bf + Bbase + (ntile * 128 + row) * Bstride + kt * 64 + (kb >> 1);
        async_ld16(g, ldsB + j * 4096 + wbase);
      }
    }
    __syncthreads();
#pragma unroll
    for (int ks = 0; ks < 2; ++ks) {
      bf16x8 af[4], bfr[4];
#pragma unroll
      for (int mb = 0; mb < 4; ++mb) {
        int m = wm * 64 + mb * 16 + l16;
        int kb = (ks * 64 + quad * 16) ^ ((m & 7) * 16);
        af[mb] = *(const bf16x8*)(ldsA + m * 128 + kb);
      }
#pragma unroll
      for (int nb = 0; nb < 4; ++nb) {
        int nn = wn * 64 + nb * 16 + l16;
        int kb = (ks * 64 + quad * 16) ^ ((nn & 7) * 16);
        bfr[nb] = *(const bf16x8*)(ldsB + nn * 128 + kb);
      }
#pragma unroll
      for (int mb = 0; mb < 4; ++mb)
#pragma unroll
        for (int nb = 0; nb < 4; ++nb)
          acc[mb][nb] = __builtin_amdgcn_mfma_f32_16x16x32_bf16(af[mb], bfr[nb], acc[mb][nb], 0, 0, 0);
    }
  }
  __bf16* outp = hw + p * (NL * NV) + mtile * 128 * NV + ntile * 128;
#pragma unroll
  for (int mb = 0; mb < 4; ++mb) {
#pragma unroll
    for (int r = 0; r < 4; ++r) {
      int ml = wm * 64 + mb * 16 + quad * 4 + r;
      float bv = bias[mtile * 128 + ml];
#pragma unroll
      for (int nb = 0; nb < 4; ++nb) {
        int nl = wn * 64 + nb * 16 + l16;
        outp[ml * NV + nl] = (__bf16)(acc[mb][nb][r] + bv);
      }
    }
  }
}

// ---------------- GEMM 2: h' = alpha*x + beta*(a @ hw) ----------------
__global__ __launch_bounds__(256, 2)
void k_gemm_a(const __bf16* __restrict__ abuf, const __bf16* __restrict__ hw,
              const float* __restrict__ x, __bf16* __restrict__ hout) {
  __shared__ __align__(16) char lds[32768];
  char* ldsA = lds;
  char* ldsB = lds + 16384;

  const int tid = threadIdx.x;
  const int bid = blockIdx.x;
  const int n = bid >> 8;
  const int mtile = (bid >> 6) & 3;
  const int ntile = bid & 63;

  const __bf16* Ab = abuf + n * (NV * NV) + mtile * 128 * NV;
  const __bf16* Bb = hw + n * (NC * NL * NV) + ntile * 128 * NV;

  const int wave = tid >> 6, lane = tid & 63;
  const int quad = lane >> 4, l16 = lane & 15;
  const int wm = wave >> 1, wn = wave & 1;
  const int wbase = (tid & ~63) * 16;

  f32x4 acc[4][4];
#pragma unroll
  for (int i = 0; i < 4; ++i)
#pragma unroll
    for (int j = 0; j < 4; ++j) acc[i][j] = (f32x4){0.f, 0.f, 0.f, 0.f};

  for (int kt = 0; kt < 512 / 64; ++kt) {
    __syncthreads();
#pragma unroll
    for (int j = 0; j < 4; ++j) {
      int pos = j * 4096 + tid * 16;
      int row = pos >> 7;
      int kb = (pos & 127) ^ ((row & 7) * 16);
      async_ld16(Ab + row * NV + kt * 64 + (kb >> 1), ldsA + j * 4096 + wbase);
    }
#pragma unroll
    for (int j = 0; j < 4; ++j) {
      int pos = j * 4096 + tid * 16;
      int row = pos >> 7;
      int kb = (pos & 127) ^ ((row & 7) * 16);
      async_ld16(Bb + row * NV + kt * 64 + (kb >> 1), ldsB + j * 4096 + wbase);
    }
    __syncthreads();
#pragma unroll
    for (int ks = 0; ks < 2; ++ks) {
      bf16x8 af[4], bfr[4];
#pragma unroll
      for (int mb = 0; mb < 4; ++mb) {
        int m = wm * 64 + mb * 16 + l16;
        int kb = (ks * 64 + quad * 16) ^ ((m & 7) * 16);
        af[mb] = *(const bf16x8*)(ldsA + m * 128 + kb);
      }
#pragma unroll
      for (int nb = 0; nb < 4; ++nb) {
        int nn = wn * 64 + nb * 16 + l16;
        int kb = (ks * 64 + quad * 16) ^ ((nn & 7) * 16);
        bfr[nb] = *(const bf16x8*)(ldsB + nn * 128 + kb);
      }
#pragma unroll
      for (int mb = 0; mb < 4; ++mb)
#pragma unroll
        for (int nb = 0; nb < 4; ++nb)
          acc[mb][nb] = __builtin_amdgcn_mfma_f32_16x16x32_bf16(af[mb], bfr[nb], acc[mb][nb], 0, 0, 0);
    }
  }
#pragma unroll
  for (int mb = 0; mb < 4; ++mb) {
#pragma unroll
    for (int r = 0; r < 4; ++r) {
      int v = mtile * 128 + wm * 64 + mb * 16 + quad * 4 + r;
#pragma unroll
      for (int nb = 0; nb < 4; ++nb) {
        int col = ntile * 128 + wn * 64 + nb * 16 + l16;
        int c = col >> 8, l = col & 255;
        float xv = x[((n * NC + c) * NV + v) * NL + l];
        hout[n * (NV * NC * NL) + v * (NC * NL) + col] =
            (__bf16)(F_ALPHA * xv + F_BETA * acc[mb][nb][r]);
      }
    }
  }
}

// ---------------- conv (vector fp32, 2 l per thread -> no spill) ----------------
// out[n,o,v,l] = cb[o] + sum_{k<96} w2[o,k]*cat(x,h1,h2)[n,k,v,l]
// 2048 blocks: n(8) x vpair(256). Block: 2 v; thread owns (v, 2 consecutive l).
__global__ __launch_bounds__(256, 2)
void k_conv_vec2(const float* __restrict__ x, const __bf16* __restrict__ h1,
                 const __bf16* __restrict__ h2, const float* __restrict__ cw,
                 const float* __restrict__ cb, float* __restrict__ out) {
  __shared__ float w2s[32 * 96];  // 12 KiB, wave-uniform broadcast reads only
  const int tid = threadIdx.x;
  for (int i = tid; i < 32 * 96; i += 256) w2s[i] = cw[i];
  __syncthreads();

  const int bid = blockIdx.x;
  const int n = bid >> 8;
  const int v = ((bid & 255) << 1) + (tid >> 7);
  const int l = (tid & 127) << 1;

  const float*  px = x  + (n * NC * NV + v) * NL + l;     // + c*(NV*NL)
  const __bf16* p1 = h1 + (n * NV + v) * (NC * NL) + l;   // + c*NL
  const __bf16* p2 = h2 + (n * NV + v) * (NC * NL) + l;

  f32x2 acc[32];
#pragma unroll
  for (int o = 0; o < 32; ++o) acc[o] = (f32x2){0.f, 0.f};

#pragma unroll
  for (int kb = 0; kb < 12; ++kb) {
    f32x2 val[8];
#pragma unroll
    for (int j = 0; j < 8; ++j) {
      int k = kb * 8 + j;
      if (k < 32) {
        float2 t = *(const float2*)(px + k * (NV * NL));
        val[j] = (f32x2){t.x, t.y};
      } else if (k < 64) {
        bf16x2 t = *(const bf16x2*)(p1 + (k - 32) * NL);
        val[j] = (f32x2){(float)t[0], (float)t[1]};
      } else {
        bf16x2 t = *(const bf16x2*)(p2 + (k - 64) * NL);
        val[j] = (f32x2){(float)t[0], (float)t[1]};
      }
    }
#pragma unroll
    for (int o = 0; o < 32; ++o) {
      const float* wr = &w2s[o * 96 + kb * 8];
      f32x4 wA = *(const f32x4*)wr;
      f32x4 wB = *(const f32x4*)(wr + 4);
      acc[o] += val[0] * wA[0];
      acc[o] += val[1] * wA[1];
      acc[o] += val[2] * wA[2];
      acc[o] += val[3] * wA[3];
      acc[o] += val[4] * wB[0];
      acc[o] += val[5] * wB[1];
      acc[o] += val[6] * wB[2];
      acc[o] += val[7] * wB[3];
    }
  }

  float* po = out + (n * NC * NV + v) * NL + l;            // + o*(NV*NL)
#pragma unroll
  for (int o = 0; o < 32; ++o) {
    float bo = cb[o];
    f32x2 r = acc[o];
    float2 s = {r[0] + bo, r[1] + bo};
    *(float2*)(po + o * (NV * NL)) = s;
  }
}

// ---------------- launch ----------------
extern "C" void kernel_launch(void* const* d_in, const int* in_sizes, int n_in,
                              void* d_out, int out_size, void* d_ws, size_t ws_size,
                              hipStream_t stream) {
  const float* x   = (const float*)d_in[0];
  const float* adj = (const float*)d_in[1];
  const float* W   = (const float*)d_in[2];
  const float* b   = (const float*)d_in[3];
  const float* cw  = (const float*)d_in[4];
  const float* cb  = (const float*)d_in[5];
  float* out = (float*)d_out;
  char* ws = (char*)d_ws;

  float*  dinv    = (float*)ws;
  float*  partial = (float*)(ws + 16384);
  __bf16* Wt      = (__bf16*)(ws + 147456);
  __bf16* abuf    = (__bf16*)(ws + 278528);
  __bf16* hwbuf   = (__bf16*)(ws + 4472832);
  __bf16* h1      = (__bf16*)(ws + 4472832 + 67108864);
  __bf16* h2      = (__bf16*)(ws + 4472832 + 2 * 67108864);

  k_colsum_part<<<128, 256, 0, stream>>>(adj, partial);
  k_dinv<<<16, 256, 0, stream>>>(partial, dinv);
  k_prep_a<<<8192, 256, 0, stream>>>(adj, dinv, abuf);
  k_prep_wt<<<256, 256, 0, stream>>>(W, Wt);

  k_gemm_wt<true><<<2048, 256, 0, stream>>>(Wt, (const void*)x, b, hwbuf);
  k_gemm_a<<<2048, 256, 0, stream>>>(abuf, hwbuf, x, h1);
  k_gemm_wt<false><<<2048, 256, 0, stream>>>(Wt, (const void*)h1, b, hwbuf);
  k_gemm_a<<<2048, 256, 0, stream>>>(abuf, hwbuf, x, h2);

  k_conv_vec2<<<2048, 256, 0, stream>>>(x, h1, h2, cw, cb, out);
}

// Round 4
// 541.798 us; speedup vs baseline: 1.6199x; 1.0027x over previous
//
#include <hip/hip_runtime.h>

// Problem constants
constexpr int NB = 8;    // batch
constexpr int NC = 32;   // channels
constexpr int NV = 512;  // vertices
constexpr int NL = 256;  // features
constexpr float F_ALPHA = 0.05f;
constexpr float F_BETA  = 0.95f;

typedef __bf16 bf16x8 __attribute__((ext_vector_type(8)));
typedef __bf16 bf16x2 __attribute__((ext_vector_type(2)));
typedef float  f32x4  __attribute__((ext_vector_type(4)));
typedef float  f32x2  __attribute__((ext_vector_type(2)));

// async global->LDS, 16B per lane; LDS dest = wave-uniform base + lane*16
__device__ __forceinline__ void async_ld16(const void* g, void* l) {
  __builtin_amdgcn_global_load_lds(
      (const __attribute__((address_space(1))) void*)g,
      (__attribute__((address_space(3))) void*)l, 16, 0, 0);
}

// ---------------- prep kernels ----------------

__global__ void k_colsum_part(const float* __restrict__ adj, float* __restrict__ partial) {
  int idx = blockIdx.x * 256 + threadIdx.x;       // NB*8*NV = 32768
  int w = idx & 511;
  int chunk = (idx >> 9) & 7;
  int n = idx >> 12;
  const float* p = adj + n * (NV * NV) + chunk * 64 * NV + w;
  float s = 0.f;
#pragma unroll
  for (int v = 0; v < 64; ++v) s += p[v * NV];
  partial[idx] = s;
}

__global__ void k_dinv(const float* __restrict__ partial, float* __restrict__ dinv) {
  int idx = blockIdx.x * 256 + threadIdx.x;       // NB*NV = 4096
  int w = idx & 511;
  int n = idx >> 9;
  float s = 1.f;
#pragma unroll
  for (int j = 0; j < 8; ++j) s += partial[n * 4096 + j * 512 + w];
  dinv[idx] = 1.f / s;
}

__global__ void k_prep_a(const float* __restrict__ adj, const float* __restrict__ dinv,
                         __bf16* __restrict__ a) {
  int idx = blockIdx.x * 256 + threadIdx.x;       // NB*NV*NV
  int w = idx & 511;
  int v = (idx >> 9) & 511;
  int n = idx >> 18;
  float val = adj[idx] + (v == w ? 1.0f : 0.0f);
  a[idx] = (__bf16)(val * dinv[(n << 9) | w]);
}

__global__ void k_prep_wt(const float* __restrict__ W, __bf16* __restrict__ Wt) {
  int idx = blockIdx.x * 256 + threadIdx.x;       // 65536
  int l = idx >> 8, k = idx & 255;
  Wt[idx] = (__bf16)W[(k << 8) | l];
}

// ---------------- GEMM 1: hw^T = Wt @ h^T + b ----------------
// bid swizzle: xcd3=bid&7 -> {ntile(2b), pbit(1b)}; mtile=(bid>>3)&1; rest=bid>>4.
// The 2 mtiles sharing a B(x) tile have bids differing by 8 -> same XCD -> L2 reuse.
template <bool BF32>
__global__ __launch_bounds__(256, 3)
void k_gemm_wt(const __bf16* __restrict__ Wt, const void* __restrict__ Bsrc,
               const float* __restrict__ bias, __bf16* __restrict__ hw) {
  __shared__ __align__(16) char lds[32768];
  char* ldsA = lds;
  char* ldsB = lds + 16384;

  const int tid = threadIdx.x;
  const int bid = blockIdx.x;
  const int xcd3 = bid & 7;
  const int mtile = (bid >> 3) & 1;
  const int rest = bid >> 4;                 // 0..127
  const int ntile = xcd3 & 3;
  const int p = (rest << 1) | (xcd3 >> 2);   // 0..255
  const int n = p >> 5, c = p & 31;

  int Bbase, Bstride;
  if (BF32) { Bbase = p * (NV * NL); Bstride = NL; }
  else      { Bbase = n * (NV * NC * NL) + c * NL; Bstride = NC * NL; }

  const int wave = tid >> 6, lane = tid & 63;
  const int quad = lane >> 4, l16 = lane & 15;
  const int wm = wave >> 1, wn = wave & 1;
  const int wbase = (tid & ~63) * 16;

  f32x4 acc[4][4];
#pragma unroll
  for (int i = 0; i < 4; ++i)
#pragma unroll
    for (int j = 0; j < 4; ++j) acc[i][j] = (f32x4){0.f, 0.f, 0.f, 0.f};

  for (int kt = 0; kt < 256 / 64; ++kt) {
    __syncthreads();
#pragma unroll
    for (int j = 0; j < 4; ++j) {
      int pos = j * 4096 + tid * 16;
      int row = pos >> 7;
      int kb = (pos & 127) ^ ((row & 7) * 16);
      const __bf16* g = Wt + (mtile * 128 + row) * 256 + kt * 64 + (kb >> 1);
      async_ld16(g, ldsA + j * 4096 + wbase);
    }
    if (BF32) {
      const float* Bf = (const float*)Bsrc;
#pragma unroll
      for (int j = 0; j < 4; ++j) {
        int pos = j * 4096 + tid * 16;
        int row = pos >> 7;
        int kb = (pos & 127) ^ ((row & 7) * 16);
        const float* g = Bf + Bbase + (ntile * 128 + row) * Bstride + kt * 64 + (kb >> 1);
        float4 f0 = *(const float4*)g;
        float4 f1 = *(const float4*)(g + 4);
        bf16x8 vv;
        vv[0] = (__bf16)f0.x; vv[1] = (__bf16)f0.y; vv[2] = (__bf16)f0.z; vv[3] = (__bf16)f0.w;
        vv[4] = (__bf16)f1.x; vv[5] = (__bf16)f1.y; vv[6] = (__bf16)f1.z; vv[7] = (__bf16)f1.w;
        *(bf16x8*)(ldsB + pos) = vv;
      }
    } else {
      const __bf16* Bf = (const __bf16*)Bsrc;
#pragma unroll
      for (int j = 0; j < 4; ++j) {
        int pos = j * 4096 + tid * 16;
        int row = pos >> 7;
        int kb = (pos & 127) ^ ((row & 7) * 16);
        const __bf16* g = Bf + Bbase + (ntile * 128 + row) * Bstride + kt * 64 + (kb >> 1);
        async_ld16(g, ldsB + j * 4096 + wbase);
      }
    }
    __syncthreads();
#pragma unroll
    for (int ks = 0; ks < 2; ++ks) {
      bf16x8 af[4], bfr[4];
#pragma unroll
      for (int mb = 0; mb < 4; ++mb) {
        int m = wm * 64 + mb * 16 + l16;
        int kb = (ks * 64 + quad * 16) ^ ((m & 7) * 16);
        af[mb] = *(const bf16x8*)(ldsA + m * 128 + kb);
      }
#pragma unroll
      for (int nb = 0; nb < 4; ++nb) {
        int nn = wn * 64 + nb * 16 + l16;
        int kb = (ks * 64 + quad * 16) ^ ((nn & 7) * 16);
        bfr[nb] = *(const bf16x8*)(ldsB + nn * 128 + kb);
      }
#pragma unroll
      for (int mb = 0; mb < 4; ++mb)
#pragma unroll
        for (int nb = 0; nb < 4; ++nb)
          acc[mb][nb] = __builtin_amdgcn_mfma_f32_16x16x32_bf16(af[mb], bfr[nb], acc[mb][nb], 0, 0, 0);
    }
  }
  __bf16* outp = hw + p * (NL * NV) + mtile * 128 * NV + ntile * 128;
#pragma unroll
  for (int mb = 0; mb < 4; ++mb) {
#pragma unroll
    for (int r = 0; r < 4; ++r) {
      int ml = wm * 64 + mb * 16 + quad * 4 + r;
      float bv = bias[mtile * 128 + ml];
#pragma unroll
      for (int nb = 0; nb < 4; ++nb) {
        int nl = wn * 64 + nb * 16 + l16;
        outp[ml * NV + nl] = (__bf16)(acc[mb][nb][r] + bv);
      }
    }
  }
}

// ---------------- GEMM 2: h' = alpha*x + beta*(a @ hw) ----------------
// bid swizzle: xcd3=bid&7; mtile=(bid>>3)&3; rest=bid>>5 (0..63); n=rest>>3;
// ntile=((rest&7)<<3)|xcd3. The 4 mtiles sharing a B tile land on one XCD.
__global__ __launch_bounds__(256, 3)
void k_gemm_a(const __bf16* __restrict__ abuf, const __bf16* __restrict__ hw,
              const float* __restrict__ x, __bf16* __restrict__ hout) {
  __shared__ __align__(16) char lds[32768];
  char* ldsA = lds;
  char* ldsB = lds + 16384;

  const int tid = threadIdx.x;
  const int bid = blockIdx.x;
  const int xcd3 = bid & 7;
  const int mtile = (bid >> 3) & 3;
  const int rest = bid >> 5;                 // 0..63
  const int n = rest >> 3;
  const int ntile = ((rest & 7) << 3) | xcd3;

  const __bf16* Ab = abuf + n * (NV * NV) + mtile * 128 * NV;
  const __bf16* Bb = hw + n * (NC * NL * NV) + ntile * 128 * NV;

  const int wave = tid >> 6, lane = tid & 63;
  const int quad = lane >> 4, l16 = lane & 15;
  const int wm = wave >> 1, wn = wave & 1;
  const int wbase = (tid & ~63) * 16;

  f32x4 acc[4][4];
#pragma unroll
  for (int i = 0; i < 4; ++i)
#pragma unroll
    for (int j = 0; j < 4; ++j) acc[i][j] = (f32x4){0.f, 0.f, 0.f, 0.f};

  for (int kt = 0; kt < 512 / 64; ++kt) {
    __syncthreads();
#pragma unroll
    for (int j = 0; j < 4; ++j) {
      int pos = j * 4096 + tid * 16;
      int row = pos >> 7;
      int kb = (pos & 127) ^ ((row & 7) * 16);
      async_ld16(Ab + row * NV + kt * 64 + (kb >> 1), ldsA + j * 4096 + wbase);
    }
#pragma unroll
    for (int j = 0; j < 4; ++j) {
      int pos = j * 4096 + tid * 16;
      int row = pos >> 7;
      int kb = (pos & 127) ^ ((row & 7) * 16);
      async_ld16(Bb + row * NV + kt * 64 + (kb >> 1), ldsB + j * 4096 + wbase);
    }
    __syncthreads();
#pragma unroll
    for (int ks = 0; ks < 2; ++ks) {
      bf16x8 af[4], bfr[4];
#pragma unroll
      for (int mb = 0; mb < 4; ++mb) {
        int m = wm * 64 + mb * 16 + l16;
        int kb = (ks * 64 + quad * 16) ^ ((m & 7) * 16);
        af[mb] = *(const bf16x8*)(ldsA + m * 128 + kb);
      }
#pragma unroll
      for (int nb = 0; nb < 4; ++nb) {
        int nn = wn * 64 + nb * 16 + l16;
        int kb = (ks * 64 + quad * 16) ^ ((nn & 7) * 16);
        bfr[nb] = *(const bf16x8*)(ldsB + nn * 128 + kb);
      }
#pragma unroll
      for (int mb = 0; mb < 4; ++mb)
#pragma unroll
        for (int nb = 0; nb < 4; ++nb)
          acc[mb][nb] = __builtin_amdgcn_mfma_f32_16x16x32_bf16(af[mb], bfr[nb], acc[mb][nb], 0, 0, 0);
    }
  }
#pragma unroll
  for (int mb = 0; mb < 4; ++mb) {
#pragma unroll
    for (int r = 0; r < 4; ++r) {
      int v = mtile * 128 + wm * 64 + mb * 16 + quad * 4 + r;
#pragma unroll
      for (int nb = 0; nb < 4; ++nb) {
        int col = ntile * 128 + wn * 64 + nb * 16 + l16;
        int c = col >> 8, l = col & 255;
        float xv = x[((n * NC + c) * NV + v) * NL + l];
        hout[n * (NV * NC * NL) + v * (NC * NL) + col] =
            (__bf16)(F_ALPHA * xv + F_BETA * acc[mb][nb][r]);
      }
    }
  }
}

// ---------------- conv (vector fp32, 2 l per thread; 4 blocks/CU) ----------------
__global__ __launch_bounds__(256, 4)
void k_conv_vec2(const float* __restrict__ x, const __bf16* __restrict__ h1,
                 const __bf16* __restrict__ h2, const float* __restrict__ cw,
                 const float* __restrict__ cb, float* __restrict__ out) {
  __shared__ float w2s[32 * 96];  // 12 KiB, wave-uniform broadcast reads only
  const int tid = threadIdx.x;
  for (int i = tid; i < 32 * 96; i += 256) w2s[i] = cw[i];
  __syncthreads();

  const int bid = blockIdx.x;
  const int n = bid >> 8;
  const int v = ((bid & 255) << 1) + (tid >> 7);
  const int l = (tid & 127) << 1;

  const float*  px = x  + (n * NC * NV + v) * NL + l;     // + c*(NV*NL)
  const __bf16* p1 = h1 + (n * NV + v) * (NC * NL) + l;   // + c*NL
  const __bf16* p2 = h2 + (n * NV + v) * (NC * NL) + l;

  f32x2 acc[32];
#pragma unroll
  for (int o = 0; o < 32; ++o) acc[o] = (f32x2){0.f, 0.f};

#pragma unroll
  for (int kb = 0; kb < 12; ++kb) {
    f32x2 val[8];
#pragma unroll
    for (int j = 0; j < 8; ++j) {
      int k = kb * 8 + j;
      if (k < 32) {
        float2 t = *(const float2*)(px + k * (NV * NL));
        val[j] = (f32x2){t.x, t.y};
      } else if (k < 64) {
        bf16x2 t = *(const bf16x2*)(p1 + (k - 32) * NL);
        val[j] = (f32x2){(float)t[0], (float)t[1]};
      } else {
        bf16x2 t = *(const bf16x2*)(p2 + (k - 64) * NL);
        val[j] = (f32x2){(float)t[0], (float)t[1]};
      }
    }
#pragma unroll
    for (int o = 0; o < 32; ++o) {
      const float* wr = &w2s[o * 96 + kb * 8];
      f32x4 wA = *(const f32x4*)wr;
      f32x4 wB = *(const f32x4*)(wr + 4);
      acc[o] += val[0] * wA[0];
      acc[o] += val[1] * wA[1];
      acc[o] += val[2] * wA[2];
      acc[o] += val[3] * wA[3];
      acc[o] += val[4] * wB[0];
      acc[o] += val[5] * wB[1];
      acc[o] += val[6] * wB[2];
      acc[o] += val[7] * wB[3];
    }
  }

  float* po = out + (n * NC * NV + v) * NL + l;            // + o*(NV*NL)
#pragma unroll
  for (int o = 0; o < 32; ++o) {
    float bo = cb[o];
    f32x2 r = acc[o];
    float2 s = {r[0] + bo, r[1] + bo};
    *(float2*)(po + o * (NV * NL)) = s;
  }
}

// ---------------- launch ----------------
extern "C" void kernel_launch(void* const* d_in, const int* in_sizes, int n_in,
                              void* d_out, int out_size, void* d_ws, size_t ws_size,
                              hipStream_t stream) {
  const float* x   = (const float*)d_in[0];
  const float* adj = (const float*)d_in[1];
  const float* W   = (const float*)d_in[2];
  const float* b   = (const float*)d_in[3];
  const float* cw  = (const float*)d_in[4];
  const float* cb  = (const float*)d_in[5];
  float* out = (float*)d_out;
  char* ws = (char*)d_ws;

  float*  dinv    = (float*)ws;
  float*  partial = (float*)(ws + 16384);
  __bf16* Wt      = (__bf16*)(ws + 147456);
  __bf16* abuf    = (__bf16*)(ws + 278528);
  __bf16* hwbuf   = (__bf16*)(ws + 4472832);
  __bf16* h1      = (__bf16*)(ws + 4472832 + 67108864);
  __bf16* h2      = (__bf16*)(ws + 4472832 + 2 * 67108864);

  k_colsum_part<<<128, 256, 0, stream>>>(adj, partial);
  k_dinv<<<16, 256, 0, stream>>>(partial, dinv);
  k_prep_a<<<8192, 256, 0, stream>>>(adj, dinv, abuf);
  k_prep_wt<<<256, 256, 0, stream>>>(W, Wt);

  k_gemm_wt<true><<<2048, 256, 0, stream>>>(Wt, (const void*)x, b, hwbuf);
  k_gemm_a<<<2048, 256, 0, stream>>>(abuf, hwbuf, x, h1);
  k_gemm_wt<false><<<2048, 256, 0, stream>>>(Wt, (const void*)h1, b, hwbuf);
  k_gemm_a<<<2048, 256, 0, stream>>>(abuf, hwbuf, x, h2);

  k_conv_vec2<<<2048, 256, 0, stream>>>(x, h1, h2, cw, cb, out);
}